// Round 11
// baseline (273.519 us; speedup 1.0000x reference)
//
#include <hip/hip_runtime.h>
#include <hip/hip_bf16.h>
#include <math.h>

#define N_NODES 50000
#define N_EDGES 800000
#define IN_DIM  128
#define MEM_DIM 32
#define OUT_DIM 64
#define NB_SCAN ((N_NODES + 255) / 256)   // 196
#define SCALE   0.17677669529663687f      // 1/sqrt(32)

typedef __attribute__((ext_vector_type(8))) short bf16x8;
typedef __attribute__((ext_vector_type(4))) float f32x4;

__device__ __forceinline__ short f2bf(float f) {
    union { float f; unsigned u; } v; v.f = f;
    unsigned r = v.u + 0x7FFF + ((v.u >> 16) & 1);   // round-to-nearest-even
    return (short)(r >> 16);
}
__device__ __forceinline__ float lo16(unsigned u) { return __uint_as_float(u << 16); }
__device__ __forceinline__ float hi16(unsigned u) { return __uint_as_float(u & 0xffff0000u); }

// ---------------------------------------------------------------------------
// prep_k: transposed bf16 weight bank wtb[m][col][k] (B-frag = one dwordx4).
// m: 0=Wq*S, 1=Wk, 2=Wv, 3=Wskip, 4=WqE*S (We_k folded into Wq). Also zeroes
// the 8-replica histogram.
// ---------------------------------------------------------------------------
__global__ __launch_bounds__(256) void prep_k(
    const float* __restrict__ Wq, const float* __restrict__ Wk,
    const float* __restrict__ Wv, const float* __restrict__ Wskip,
    const float* __restrict__ We_k, unsigned short* __restrict__ wtb,
    int* __restrict__ cntr)
{
    const int i = blockIdx.x * 256 + threadIdx.x;   // 1600*256 = 409600
    if (i < 8 * N_NODES) cntr[i] = 0;
    if (i >= 51200) return;                         // 5*64*160
    const int m = i / 10240, rem = i % 10240, c = rem / 160, k = rem % 160;
    float v;
    if (m == 4) {
        const int h = c >> 5, kk = c & 31;
        v = 0.f;
        #pragma unroll
        for (int j = 0; j < 32; ++j)
            v += Wq[k * 64 + h * 32 + j] * We_k[kk * 64 + h * 32 + j];
        v *= SCALE;
    } else {
        const float* W = (m == 0) ? Wq : (m == 1) ? Wk : (m == 2) ? Wv : Wskip;
        v = W[k * 64 + c];
        if (m == 0) v *= SCALE;
    }
    wtb[(size_t)(m * 64 + c) * 160 + k] = (unsigned short)f2bf(v);
}

// ---------------------------------------------------------------------------
// Kernel A: PURE node GEMM [N,160]@[160, 5x64] -> zqp, zkv, qekp (bf16),
// out (skip, f32). 5 waves; wave = matrix; B-frags single 16B loads.
// ---------------------------------------------------------------------------
__global__ __launch_bounds__(320) void node_gemm(
    const float* __restrict__ x, const float* __restrict__ mem,
    const unsigned short* __restrict__ wtb,
    unsigned short* __restrict__ zqp, unsigned short* __restrict__ zkv,
    unsigned short* __restrict__ qekp, float* __restrict__ out)
{
    const int tid  = threadIdx.x;
    const int w    = tid >> 6;                  // 0..4
    const int lane = tid & 63;
    const int l15  = lane & 15;
    const int quad = lane >> 4;
    const int nb   = blockIdx.x * 16;

    const unsigned short* WmT = wtb + (size_t)w * 64 * 160;

    f32x4 acc[4];
    #pragma unroll
    for (int g = 0; g < 4; ++g) acc[g] = (f32x4)0.0f;

    const int node = nb + l15;
    #pragma unroll
    for (int kb = 0; kb < 5; ++kb) {
        const float* zsrc = (kb < 4)
            ? (x   + (size_t)node * IN_DIM  + kb * 32 + quad * 8)
            : (mem + (size_t)node * MEM_DIM + quad * 8);
        bf16x8 afrag;
        #pragma unroll
        for (int j = 0; j < 8; ++j) afrag[j] = f2bf(zsrc[j]);

        const int k0 = kb * 32 + quad * 8;
        #pragma unroll
        for (int g = 0; g < 4; ++g) {
            const bf16x8 bfrag = *(const bf16x8*)(WmT + (size_t)(16 * g + l15) * 160 + k0);
            acc[g] = __builtin_amdgcn_mfma_f32_16x16x32_bf16(afrag, bfrag, acc[g], 0, 0, 0);
        }
    }
    #pragma unroll
    for (int g = 0; g < 4; ++g) {
        #pragma unroll
        for (int r = 0; r < 4; ++r) {
            const int nrow = nb + quad * 4 + r;
            const int col  = 16 * g + l15;
            if (w == 3)
                out[(size_t)nrow * OUT_DIM + col] = acc[g][r];
            else if (w == 0)
                zqp[(size_t)nrow * 64 + col] = (unsigned short)f2bf(acc[g][r]);
            else if (w == 4)
                qekp[(size_t)nrow * 64 + col] = (unsigned short)f2bf(acc[g][r]);
            else
                zkv[(size_t)nrow * 128 + (w == 2 ? 64 : 0) + col] =
                    (unsigned short)f2bf(acc[g][r]);
        }
    }
}

// ---------------------------------------------------------------------------
// hist_k: 8-replica dst histogram + rank capture. replica = (e>>8)&7.
// ---------------------------------------------------------------------------
__global__ __launch_bounds__(256) void hist_k(
    const int* __restrict__ dst, int* __restrict__ cntr, int* __restrict__ rank)
{
    const int e = blockIdx.x * 256 + threadIdx.x;   // 3125*256 == E
    rank[e] = atomicAdd(&cntr[(blockIdx.x & 7) * N_NODES + dst[e]], 1);
}

// ---------------------------------------------------------------------------
// scan1/scan2 (2-level; consumers add bsum[d>>8])
// ---------------------------------------------------------------------------
__global__ __launch_bounds__(256) void scan1_k(int* __restrict__ cntr,
                                               int* __restrict__ base,
                                               int* __restrict__ bsum,
                                               int* __restrict__ deg)
{
    __shared__ int sh[256];
    const int i = blockIdx.x * 256 + threadIdx.x;
    int tot = 0;
    if (i < N_NODES) {
        int off = 0;
        #pragma unroll
        for (int r = 0; r < 8; ++r) {
            const int c = cntr[r * N_NODES + i];
            cntr[r * N_NODES + i] = off;
            off += c;
        }
        tot = off;
        deg[i] = tot;
    }
    sh[threadIdx.x] = tot;
    __syncthreads();
    int val = tot;
    for (int off = 1; off < 256; off <<= 1) {
        const int y = (threadIdx.x >= off) ? sh[threadIdx.x - off] : 0;
        __syncthreads();
        val += y; sh[threadIdx.x] = val;
        __syncthreads();
    }
    if (i < N_NODES) base[i] = val - tot;
    if (threadIdx.x == 255) bsum[blockIdx.x] = val;
}

__global__ __launch_bounds__(256) void scan2_k(int* __restrict__ bsum)
{
    __shared__ int sh[256];
    const int i = threadIdx.x;
    const int v = (i < NB_SCAN) ? bsum[i] : 0;
    sh[i] = v;
    __syncthreads();
    int val = v;
    for (int off = 1; off < 256; off <<= 1) {
        const int y = (i >= off) ? sh[i - off] : 0;
        __syncthreads();
        val += y; sh[i] = val;
        __syncthreads();
    }
    if (i < NB_SCAN) bsum[i] = val - v;
}

// ---------------------------------------------------------------------------
// score_scatter_k: edge-parallel, TWO edges per thread for 2x memory-level
// parallelism (12 independent gathers in flight per lane). 4 lanes/edge
// (lane = eidx + 16*g; group g covers k-dims [16g,16g+16)). Writes the
// record (src, t, pe0, pe1) directly to its dst-sorted slot.
// ---------------------------------------------------------------------------
__global__ __launch_bounds__(256) void score_scatter_k(
    const int* __restrict__ srcA, const int* __restrict__ dstA,
    const float* __restrict__ tA,
    const float* __restrict__ w_time, const float* __restrict__ b_time,
    const unsigned short* __restrict__ zqp,
    const unsigned short* __restrict__ qekp,
    const unsigned short* __restrict__ zkv,
    const int* __restrict__ base, const int* __restrict__ bsum,
    const int* __restrict__ cntr, const int* __restrict__ rank,
    float4* __restrict__ edata2)
{
    const int tid  = threadIdx.x;
    const int w    = tid >> 6;
    const int lane = tid & 63;
    const int eidx = lane & 15;
    const int g    = lane >> 4;
    // block covers 128 edges: wave w handles [blk*128 + w*32, +32)
    const int ea = blockIdx.x * 128 + w * 32 + eidx;   // 6250*128 == E
    const int eb = ea + 16;

    const int   sa = srcA[ea], sb = srcA[eb];
    const int   da = dstA[ea], db = dstA[eb];
    const float ta = tA[ea],   tb = tA[eb];

    // group g's 16 te params (head g>>1, within-head dim (g&1)*16+i)
    const int hk16 = (g & 1) * 16;
    float wts[16], bts[16];
    #pragma unroll
    for (int i = 0; i < 16; ++i) {
        wts[i] = w_time[hk16 + i];
        bts[i] = b_time[hk16 + i];
    }

    // issue all 12 gathers up front (independent -> batch in flight)
    const uint4 qa0 = *(const uint4*)(zqp  + (size_t)da * 64 + 16 * g);
    const uint4 qa1 = *(const uint4*)(zqp  + (size_t)da * 64 + 16 * g + 8);
    const uint4 ea0 = *(const uint4*)(qekp + (size_t)da * 64 + 16 * g);
    const uint4 ea1 = *(const uint4*)(qekp + (size_t)da * 64 + 16 * g + 8);
    const uint4 ka0 = *(const uint4*)(zkv  + (size_t)sa * 128 + 16 * g);
    const uint4 ka1 = *(const uint4*)(zkv  + (size_t)sa * 128 + 16 * g + 8);
    const uint4 qb0 = *(const uint4*)(zqp  + (size_t)db * 64 + 16 * g);
    const uint4 qb1 = *(const uint4*)(zqp  + (size_t)db * 64 + 16 * g + 8);
    const uint4 eb0 = *(const uint4*)(qekp + (size_t)db * 64 + 16 * g);
    const uint4 eb1 = *(const uint4*)(qekp + (size_t)db * 64 + 16 * g + 8);
    const uint4 kb0 = *(const uint4*)(zkv  + (size_t)sb * 128 + 16 * g);
    const uint4 kb1 = *(const uint4*)(zkv  + (size_t)sb * 128 + 16 * g + 8);

    unsigned qA[8]  = {qa0.x, qa0.y, qa0.z, qa0.w, qa1.x, qa1.y, qa1.z, qa1.w};
    unsigned eA[8]  = {ea0.x, ea0.y, ea0.z, ea0.w, ea1.x, ea1.y, ea1.z, ea1.w};
    unsigned kA[8]  = {ka0.x, ka0.y, ka0.z, ka0.w, ka1.x, ka1.y, ka1.z, ka1.w};
    unsigned qB[8]  = {qb0.x, qb0.y, qb0.z, qb0.w, qb1.x, qb1.y, qb1.z, qb1.w};
    unsigned eB[8]  = {eb0.x, eb0.y, eb0.z, eb0.w, eb1.x, eb1.y, eb1.z, eb1.w};
    unsigned kB[8]  = {kb0.x, kb0.y, kb0.z, kb0.w, kb1.x, kb1.y, kb1.z, kb1.w};

    float pA = 0.f, pB = 0.f;
    #pragma unroll
    for (int i2 = 0; i2 < 8; ++i2) {
        const float teA0 = __cosf(ta * wts[2*i2]   + bts[2*i2]);
        const float teA1 = __cosf(ta * wts[2*i2+1] + bts[2*i2+1]);
        pA += teA0 * lo16(eA[i2]) + teA1 * hi16(eA[i2]);
        pA += lo16(qA[i2]) * lo16(kA[i2]) + hi16(qA[i2]) * hi16(kA[i2]);
        const float teB0 = __cosf(tb * wts[2*i2]   + bts[2*i2]);
        const float teB1 = __cosf(tb * wts[2*i2+1] + bts[2*i2+1]);
        pB += teB0 * lo16(eB[i2]) + teB1 * hi16(eB[i2]);
        pB += lo16(qB[i2]) * lo16(kB[i2]) + hi16(qB[i2]) * hi16(kB[i2]);
    }
    pA += __shfl_xor(pA, 16, 64);
    pB += __shfl_xor(pB, 16, 64);
    const float peA  = __expf(pA);              // scale pre-folded
    const float peB  = __expf(pB);
    const float peA1 = __shfl_xor(peA, 32, 64);
    const float peB1 = __shfl_xor(peB, 32, 64);

    if (g == 0) {
        {
            const int pos = base[da] + bsum[da >> 8]
                          + cntr[((ea >> 8) & 7) * N_NODES + da] + rank[ea];
            float4 rc; rc.x = __int_as_float(sa); rc.y = ta; rc.z = peA; rc.w = peA1;
            edata2[pos] = rc;
        }
        {
            const int pos = base[db] + bsum[db >> 8]
                          + cntr[((eb >> 8) & 7) * N_NODES + db] + rank[eb];
            float4 rc; rc.x = __int_as_float(sb); rc.y = tb; rc.z = peB; rc.w = peB1;
            edata2[pos] = rc;
        }
    }
}

// ---------------------------------------------------------------------------
// agg_k: one WAVE per node. Chunks of 16 sorted records, prefetched one chunk
// ahead; pe ZEROED for pad slots at staging time so the inner loop is a fixed
// fully-unrolled 16 -> all 16 v-row gathers batch-issue under one waitcnt
// (no runtime-bound serial load->wait->FMA chain). Fused We_v epilogue.
// ---------------------------------------------------------------------------
__global__ __launch_bounds__(256) void agg_k(
    const float4* __restrict__ edata2, const int* __restrict__ base,
    const int* __restrict__ bsum, const int* __restrict__ degA,
    const float* __restrict__ w_time, const float* __restrict__ b_time,
    const unsigned short* __restrict__ zkv,
    const float* __restrict__ We_v, float* __restrict__ out)
{
    __shared__ float recs[4][64];               // 1 KB; wave-private strips
    const int tid  = threadIdx.x;
    const int w    = tid >> 6;
    const int lane = tid & 63;
    const int n    = blockIdx.x * 4 + w;

    const int b0  = base[n] + bsum[n >> 8];
    const int deg = degA[n];
    float* rec = &recs[w][0];

    const float wtA = w_time[lane & 31];
    const float btA = b_time[lane & 31];

    float av = 0.f, pte = 0.f, lp = 0.f;

    // prefetch chunk 0
    float4 rc;
    if (lane < 16 && deg > 0)
        rc = edata2[min(b0 + lane, N_EDGES - 1)];

    for (int ch = 0; ch < deg; ch += 16) {
        if (lane < 16) {
            float4 rr = rc;
            if (ch + lane >= deg) { rr.z = 0.f; rr.w = 0.f; }   // pad: pe=0
            *(float4*)(rec + lane * 4) = rr;
        }
        // prefetch next chunk while processing this one
        const int nch = ch + 16;
        if (lane < 16 && nch < deg)
            rc = edata2[min(b0 + nch + lane, N_EDGES - 1)];

        #pragma unroll
        for (int j = 0; j < 16; ++j) {
            const float4 r = *(const float4*)(rec + j * 4);
            const int   srcn = __float_as_int(r.x);
            const float pej  = (lane < 32) ? r.z : r.w;
            const float v    = lo16((unsigned)zkv[(size_t)srcn * 128 + 64 + lane]);
            av  += pej * v;
            pte += pej * __cosf(r.y * wtA + btA);
            lp  += pej;
        }
    }

    // ---- fused We_v epilogue ----
    rec[lane] = pte;                            // rec[h*32+dim] layout
    float wev[32];
    #pragma unroll
    for (int k = 0; k < 32; ++k) wev[k] = We_v[k * 64 + lane];

    const float inv = (lp > 0.f) ? 1.f / lp : 0.f;
    const float* pl = rec + (lane >> 5) * 32;
    float dot = 0.f;
    #pragma unroll
    for (int k = 0; k < 32; ++k) dot += pl[k] * wev[k];

    out[(size_t)n * OUT_DIM + lane] += (av + dot) * inv;   // skip already there
}

extern "C" void kernel_launch(void* const* d_in, const int* in_sizes, int n_in,
                              void* d_out, int out_size, void* d_ws, size_t ws_size,
                              hipStream_t stream) {
    (void)in_sizes; (void)n_in; (void)out_size; (void)ws_size;
    const int*   src    = (const int*)d_in[0];
    const int*   dst    = (const int*)d_in[1];
    const float* t      = (const float*)d_in[2];
    const float* x      = (const float*)d_in[3];
    const float* mem    = (const float*)d_in[4];
    const float* w_time = (const float*)d_in[5];
    const float* b_time = (const float*)d_in[6];
    const float* Wq     = (const float*)d_in[7];
    const float* Wk     = (const float*)d_in[8];
    const float* Wv     = (const float*)d_in[9];
    const float* We_k   = (const float*)d_in[10];
    const float* We_v   = (const float*)d_in[11];
    const float* Wskip  = (const float*)d_in[12];

    // workspace layout (16B-aligned chunks)
    char* p = (char*)d_ws;
    unsigned short* zkv  = (unsigned short*)p; p += (size_t)N_NODES * 128 * 2; // 12.8 MB
    unsigned short* zqp  = (unsigned short*)p; p += (size_t)N_NODES * 64 * 2;  // 6.4 MB
    unsigned short* qekp = (unsigned short*)p; p += (size_t)N_NODES * 64 * 2;  // 6.4 MB
    unsigned short* wtb  = (unsigned short*)p; p += (size_t)5 * 64 * 160 * 2;  // 100 KB
    float4* edata2 = (float4*)p; p += (size_t)N_EDGES * 16;                    // 12.8 MB
    int*  cntr  = (int*)p;   p += (size_t)8 * N_NODES * 4;   // zeroed in prep_k
    int*  rank  = (int*)p;   p += (size_t)N_EDGES * 4;
    int*  base  = (int*)p;   p += (size_t)N_NODES * 4;
    int*  deg   = (int*)p;   p += (size_t)N_NODES * 4;
    int*  bsum  = (int*)p;   p += 256 * 4;
    float* out  = (float*)d_out;

    prep_k   <<<1600, 256, 0, stream>>>(Wq, Wk, Wv, Wskip, We_k, wtb, cntr);
    node_gemm<<<N_NODES / 16, 320, 0, stream>>>(x, mem, wtb, zqp, zkv, qekp, out);
    hist_k   <<<N_EDGES / 256, 256, 0, stream>>>(dst, cntr, rank);
    scan1_k  <<<NB_SCAN, 256, 0, stream>>>(cntr, base, bsum, deg);
    scan2_k  <<<1, 256, 0, stream>>>(bsum);
    score_scatter_k<<<N_EDGES / 128, 256, 0, stream>>>(src, dst, t, w_time, b_time,
                                                       zqp, qekp, zkv, base, bsum,
                                                       cntr, rank, edata2);
    agg_k    <<<N_NODES / 4, 256, 0, stream>>>(edata2, base, bsum, deg,
                                               w_time, b_time, zkv, We_v, out);
}